// Round 28
// baseline (512.330 us; speedup 1.0000x reference)
//
#include <hip/hip_runtime.h>
#include <hip/hip_bf16.h>
#include <math.h>

constexpr int Lc = 256;
constexpr int Hc = 16;
constexpr int Dc = 2048;
constexpr int DHc = 128;
constexpr int LD = Lc * Dc;           // 524288
constexpr int OUT_LAST = 2 * LD - 1;
constexpr int NKT2 = 32;              // K-tiles per z-split (2 x 1024)

typedef __attribute__((ext_vector_type(8))) short short8;
typedef __attribute__((ext_vector_type(4))) float f32x4;
typedef __attribute__((ext_vector_type(4))) unsigned short ushort4v;

__device__ inline short f2bf(float f) {
  __hip_bfloat16 h = __float2bfloat16(f);
  return *reinterpret_cast<short*>(&h);
}
__device__ inline float bf2f(unsigned short s) {
  unsigned int u = ((unsigned int)s) << 16;
  return *reinterpret_cast<float*>(&u);
}

#define MFMA16(a, b, c) __builtin_amdgcn_mfma_f32_16x16x32_bf16(a, b, c, 0, 0, 0)

// ---------------------------------------------------------------------------
// Stage 1 (K-split 2, depth-4 register pipeline, barrier-free):
// v_partial = x @ Wv. z=0 -> (vR0,vI0), z=1 -> (vR1,vI1), bf16.
// ---------------------------------------------------------------------------
__global__ void gemm_v_split(const float* __restrict__ x,
                             const float* __restrict__ Wr,
                             const float* __restrict__ Wi,
                             __hip_bfloat16* __restrict__ vR0_,
                             __hip_bfloat16* __restrict__ vI0_,
                             __hip_bfloat16* __restrict__ vR1_,
                             __hip_bfloat16* __restrict__ vI1_) {
  const int tid = threadIdx.x;
  const int lane = tid & 63, wv = tid >> 6;
  const int m0 = blockIdx.y * 32, n0 = blockIdx.x * 32;
  const int kbase = blockIdx.z * (NKT2 * 32);
  const int frow = lane & 15;
  const int koct = (lane >> 4) * 8;

  __hip_bfloat16* vR = blockIdx.z ? vR1_ : vR0_;
  __hip_bfloat16* vI = blockIdx.z ? vI1_ : vI0_;

  const float* xbase = x + (m0 + wv * 16 + frow) * Dc + kbase + koct;
  const float* wRb = Wr + (kbase + koct) * Dc + n0 + frow;
  const float* wIb = Wi + (kbase + koct) * Dc + n0 + frow;

  f32x4 accR[2] = {}, accI[2] = {};

#define DECLSET_V(S) f32x4 xa##S, xb##S; float bR##S[2][8], bI##S[2][8];
  DECLSET_V(0) DECLSET_V(1) DECLSET_V(2) DECLSET_V(3)

#define LOAD_V(S, KT) { const int k0_ = (KT) * 32;                            \
    xa##S = *reinterpret_cast<const f32x4*>(xbase + k0_);                     \
    xb##S = *reinterpret_cast<const f32x4*>(xbase + k0_ + 4);                 \
    _Pragma("unroll") for (int ct = 0; ct < 2; ++ct)                          \
    _Pragma("unroll") for (int j = 0; j < 8; ++j) {                           \
      bR##S[ct][j] = wRb[(k0_ + j) * Dc + ct * 16];                           \
      bI##S[ct][j] = wIb[(k0_ + j) * Dc + ct * 16]; } }

#define MF_V(S) { short8 a_;                                                  \
    a_[0]=f2bf(xa##S[0]); a_[1]=f2bf(xa##S[1]);                               \
    a_[2]=f2bf(xa##S[2]); a_[3]=f2bf(xa##S[3]);                               \
    a_[4]=f2bf(xb##S[0]); a_[5]=f2bf(xb##S[1]);                               \
    a_[6]=f2bf(xb##S[2]); a_[7]=f2bf(xb##S[3]);                               \
    _Pragma("unroll") for (int ct = 0; ct < 2; ++ct) { short8 bR_, bI_;       \
      _Pragma("unroll") for (int j = 0; j < 8; ++j) {                         \
        bR_[j] = f2bf(bR##S[ct][j]); bI_[j] = f2bf(bI##S[ct][j]); }           \
      accR[ct] = MFMA16(a_, bR_, accR[ct]);                                   \
      accI[ct] = MFMA16(a_, bI_, accI[ct]); } }

  LOAD_V(0, 0) LOAD_V(1, 1) LOAD_V(2, 2)
  for (int kt = 0; kt < NKT2; kt += 4) {
    LOAD_V(3, kt + 3)
    MF_V(0)
    if (kt + 4 < NKT2) LOAD_V(0, kt + 4)
    MF_V(1)
    if (kt + 5 < NKT2) LOAD_V(1, kt + 5)
    MF_V(2)
    if (kt + 6 < NKT2) LOAD_V(2, kt + 6)
    MF_V(3)
  }

#pragma unroll
  for (int ct = 0; ct < 2; ++ct)
#pragma unroll
    for (int r = 0; r < 4; ++r) {
      int row = m0 + wv * 16 + (lane >> 4) * 4 + r;
      int col = n0 + ct * 16 + frow;
      vR[row * Dc + col] = __float2bfloat16(accR[ct][r]);
      vI[row * Dc + col] = __float2bfloat16(accI[ct][r]);
    }
}

// ---------------------------------------------------------------------------
// Stage 2: o[s,n] = sum_m J[(m+s)%L, n/128] * (v0+v1+bv)[m,n]
// ---------------------------------------------------------------------------
__global__ void corr_v4(const __hip_bfloat16* __restrict__ vR0,
                        const __hip_bfloat16* __restrict__ vI0,
                        const __hip_bfloat16* __restrict__ vR1,
                        const __hip_bfloat16* __restrict__ vI1,
                        const float* __restrict__ bvR,
                        const float* __restrict__ bvI,
                        const float* __restrict__ JR,
                        const float* __restrict__ JI,
                        __hip_bfloat16* __restrict__ oR,
                        __hip_bfloat16* __restrict__ oI) {
  const int s = blockIdx.y;
  const int n0 = blockIdx.x * 256;
  const int tid = threadIdx.x;          // 0..63
  const int n = n0 + tid * 4;
  const int hl = (tid * 4) >> 7;
  __shared__ float jr[2][Lc], ji[2][Lc];
  const int h0 = n0 / DHc;
  for (int i = tid; i < 512; i += 64) {
    int hh = i >> 8, l = i & 255;
    jr[hh][l] = JR[l * Hc + h0 + hh];
    ji[hh][l] = JI[l * Hc + h0 + hh];
  }
  __syncthreads();

  f32x4 bvr4 = *reinterpret_cast<const f32x4*>(bvR + n);
  f32x4 bvi4 = *reinterpret_cast<const f32x4*>(bvI + n);

  float ar[4] = {0.f, 0.f, 0.f, 0.f}, ai[4] = {0.f, 0.f, 0.f, 0.f};
  const unsigned short* pR0 = reinterpret_cast<const unsigned short*>(vR0) + n;
  const unsigned short* pI0 = reinterpret_cast<const unsigned short*>(vI0) + n;
  const unsigned short* pR1 = reinterpret_cast<const unsigned short*>(vR1) + n;
  const unsigned short* pI1 = reinterpret_cast<const unsigned short*>(vI1) + n;
#pragma unroll 4
  for (int m = 0; m < Lc; ++m) {
    int l = (m + s) & (Lc - 1);
    float jjr = jr[hl][l], jji = ji[hl][l];
    ushort4v r40 = *reinterpret_cast<const ushort4v*>(pR0 + m * Dc);
    ushort4v i40 = *reinterpret_cast<const ushort4v*>(pI0 + m * Dc);
    ushort4v r41 = *reinterpret_cast<const ushort4v*>(pR1 + m * Dc);
    ushort4v i41 = *reinterpret_cast<const ushort4v*>(pI1 + m * Dc);
#pragma unroll
    for (int j = 0; j < 4; ++j) {
      float vr = bf2f(r40[j]) + bf2f(r41[j]) + bvr4[j];
      float vi = bf2f(i40[j]) + bf2f(i41[j]) + bvi4[j];
      ar[j] = fmaf(jjr, vr, ar[j]);
      ar[j] = fmaf(-jji, vi, ar[j]);
      ai[j] = fmaf(jjr, vi, ai[j]);
      ai[j] = fmaf(jji, vr, ai[j]);
    }
  }
  short oRp[4], oIp[4];
#pragma unroll
  for (int j = 0; j < 4; ++j) { oRp[j] = f2bf(ar[j]); oIp[j] = f2bf(ai[j]); }
  *reinterpret_cast<ushort4v*>(reinterpret_cast<unsigned short*>(oR) + s * Dc + n) =
      *reinterpret_cast<ushort4v*>(oRp);
  *reinterpret_cast<ushort4v*>(reinterpret_cast<unsigned short*>(oI) + s * Dc + n) =
      *reinterpret_cast<ushort4v*>(oIp);
}

// ---------------------------------------------------------------------------
// Stage 3 (K-split 2, depth-4): y_partial = o @ W0. z=0 -> p0, z=1 -> p1.
// ---------------------------------------------------------------------------
__global__ void gemm_y_split(const __hip_bfloat16* __restrict__ oR,
                             const __hip_bfloat16* __restrict__ oI,
                             const float* __restrict__ Wr,
                             const float* __restrict__ Wi,
                             __hip_bfloat16* __restrict__ pR0_,
                             __hip_bfloat16* __restrict__ pI0_,
                             __hip_bfloat16* __restrict__ pR1_,
                             __hip_bfloat16* __restrict__ pI1_) {
  const int tid = threadIdx.x;
  const int lane = tid & 63, wv = tid >> 6;
  const int m0 = blockIdx.y * 32, n0 = blockIdx.x * 32;
  const int kbase = blockIdx.z * (NKT2 * 32);
  const int frow = lane & 15;
  const int koct = (lane >> 4) * 8;

  __hip_bfloat16* pR = blockIdx.z ? pR1_ : pR0_;
  __hip_bfloat16* pI = blockIdx.z ? pI1_ : pI0_;

  const short* aRb = reinterpret_cast<const short*>(oR) + (m0 + wv * 16 + frow) * Dc + kbase + koct;
  const short* aIb = reinterpret_cast<const short*>(oI) + (m0 + wv * 16 + frow) * Dc + kbase + koct;
  const float* wRb = Wr + (kbase + koct) * Dc + n0 + frow;
  const float* wIb = Wi + (kbase + koct) * Dc + n0 + frow;

  f32x4 accR[2] = {}, accI[2] = {};

#define DECLSET_Y(S) short8 aR##S, aI##S; float yR##S[2][8], yI##S[2][8];
  DECLSET_Y(0) DECLSET_Y(1) DECLSET_Y(2) DECLSET_Y(3)

#define LOAD_Y(S, KT) { const int k0_ = (KT) * 32;                            \
    aR##S = *reinterpret_cast<const short8*>(aRb + k0_);                      \
    aI##S = *reinterpret_cast<const short8*>(aIb + k0_);                      \
    _Pragma("unroll") for (int ct = 0; ct < 2; ++ct)                          \
    _Pragma("unroll") for (int j = 0; j < 8; ++j) {                           \
      yR##S[ct][j] = wRb[(k0_ + j) * Dc + ct * 16];                           \
      yI##S[ct][j] = wIb[(k0_ + j) * Dc + ct * 16]; } }

#define MF_Y(S) { short8 aIn_;                                                \
    _Pragma("unroll") for (int j = 0; j < 8; ++j)                             \
      aIn_[j] = aI##S[j] ^ (short)0x8000;                                     \
    _Pragma("unroll") for (int ct = 0; ct < 2; ++ct) { short8 bR_, bI_;       \
      _Pragma("unroll") for (int j = 0; j < 8; ++j) {                         \
        bR_[j] = f2bf(yR##S[ct][j]); bI_[j] = f2bf(yI##S[ct][j]); }           \
      accR[ct] = MFMA16(aR##S, bR_, accR[ct]);                                \
      accR[ct] = MFMA16(aIn_, bI_, accR[ct]);                                 \
      accI[ct] = MFMA16(aR##S, bI_, accI[ct]);                                \
      accI[ct] = MFMA16(aI##S, bR_, accI[ct]); } }

  LOAD_Y(0, 0) LOAD_Y(1, 1) LOAD_Y(2, 2)
  for (int kt = 0; kt < NKT2; kt += 4) {
    LOAD_Y(3, kt + 3)
    MF_Y(0)
    if (kt + 4 < NKT2) LOAD_Y(0, kt + 4)
    MF_Y(1)
    if (kt + 5 < NKT2) LOAD_Y(1, kt + 5)
    MF_Y(2)
    if (kt + 6 < NKT2) LOAD_Y(2, kt + 6)
    MF_Y(3)
  }

#pragma unroll
  for (int ct = 0; ct < 2; ++ct)
#pragma unroll
    for (int r = 0; r < 4; ++r) {
      int row = m0 + wv * 16 + (lane >> 4) * 4 + r;
      int col = n0 + ct * 16 + frow;
      pR[row * Dc + col] = __float2bfloat16(accR[ct][r]);
      pI[row * Dc + col] = __float2bfloat16(accI[ct][r]);
    }
}

// ---------------------------------------------------------------------------
// Epilogue: y = p0 + p1 + b0; out = log_cosh(y); +1-shifted store.
// ---------------------------------------------------------------------------
__global__ void epilogue_y(const __hip_bfloat16* __restrict__ pR0b,
                           const __hip_bfloat16* __restrict__ pI0b,
                           const __hip_bfloat16* __restrict__ pR1b,
                           const __hip_bfloat16* __restrict__ pI1b,
                           const float* __restrict__ br,
                           const float* __restrict__ bi,
                           __hip_bfloat16* __restrict__ out) {
  const int idx0 = (blockIdx.x * 256 + threadIdx.x) * 4;
  const int col0 = idx0 & (Dc - 1);
  ushort4v r0 = *reinterpret_cast<const ushort4v*>(
      reinterpret_cast<const unsigned short*>(pR0b) + idx0);
  ushort4v i0 = *reinterpret_cast<const ushort4v*>(
      reinterpret_cast<const unsigned short*>(pI0b) + idx0);
  ushort4v r1 = *reinterpret_cast<const ushort4v*>(
      reinterpret_cast<const unsigned short*>(pR1b) + idx0);
  ushort4v i1 = *reinterpret_cast<const ushort4v*>(
      reinterpret_cast<const unsigned short*>(pI1b) + idx0);
  f32x4 br4 = *reinterpret_cast<const f32x4*>(br + col0);
  f32x4 bi4 = *reinterpret_cast<const f32x4*>(bi + col0);

  constexpr float LN2 = 0.69314718055994530942f;
#pragma unroll
  for (int j = 0; j < 4; ++j) {
    int idx = idx0 + j;
    float yr = bf2f(r0[j]) + bf2f(r1[j]) + br4[j];
    float yi = bf2f(i0[j]) + bf2f(i1[j]) + bi4[j];
    float sgn = (yr < 0.f) ? -1.f : 1.f;
    float zr = yr * sgn, zi = yi * sgn;
    float e = expf(-2.f * zr);
    float c = cosf(2.f * zi), s2 = sinf(2.f * zi);
    float pwr = e * c, pwi = -e * s2;
    float lr = 0.5f * log1pf(2.f * pwr + pwr * pwr + pwi * pwi);
    float li = atan2f(pwi, 1.f + pwr);
    float rr = zr + lr - LN2;
    float ri = zi + li;
    int f = idx * 2;
    out[f + 1] = __float2bfloat16(rr);        // validated[f]   = my[f+1]
    if (f + 2 <= OUT_LAST)
      out[f + 2] = __float2bfloat16(ri);      // validated[f+1] = my[f+2]
  }
}

extern "C" void kernel_launch(void* const* d_in, const int* in_sizes, int n_in,
                              void* d_out, int out_size, void* d_ws, size_t ws_size,
                              hipStream_t stream) {
  const float* x   = (const float*)d_in[0];
  const float* WvR = (const float*)d_in[1];
  const float* bvR = (const float*)d_in[2];
  const float* WvI = (const float*)d_in[3];
  const float* bvI = (const float*)d_in[4];
  const float* JR  = (const float*)d_in[5];
  const float* JI  = (const float*)d_in[6];
  const float* W0R = (const float*)d_in[7];
  const float* b0R = (const float*)d_in[8];
  const float* W0I = (const float*)d_in[9];
  const float* b0I = (const float*)d_in[10];

  // ws 4MB: quarters Q0..Q3 of 1MB (= LD bf16 elems each).
  __hip_bfloat16* Q0 = (__hip_bfloat16*)d_ws;
  __hip_bfloat16* Q1 = Q0 + LD;
  __hip_bfloat16* Q2 = Q1 + LD;
  __hip_bfloat16* Q3 = Q2 + LD;
  // d_out 2MB: halves for o planes, later final output.
  __hip_bfloat16* oR = (__hip_bfloat16*)d_out;
  __hip_bfloat16* oI = oR + LD;
  __hip_bfloat16* out = (__hip_bfloat16*)d_out;

  // Phase A: v partials (z0 -> Q0,Q1; z1 -> Q2,Q3)
  gemm_v_split<<<dim3(Dc / 32, Lc / 32, 2), 128, 0, stream>>>(
      x, WvR, WvI, Q0, Q1, Q2, Q3);
  // Phase B: corr -> o in d_out
  corr_v4<<<dim3(Dc / 256, Lc), 64, 0, stream>>>(
      Q0, Q1, Q2, Q3, bvR, bvI, JR, JI, oR, oI);
  // Phase C: y partials (z0 -> Q0,Q1; z1 -> Q2,Q3), v dead
  gemm_y_split<<<dim3(Dc / 32, Lc / 32, 2), 128, 0, stream>>>(
      oR, oI, W0R, W0I, Q0, Q1, Q2, Q3);
  // Phase D: epilogue -> d_out (+1-shifted), o dead
  epilogue_y<<<LD / 1024, 256, 0, stream>>>(
      Q0, Q1, Q2, Q3, b0R, b0I, out);
}

// Round 29
// 162.391 us; speedup vs baseline: 3.1549x; 3.1549x over previous
//
#include <hip/hip_runtime.h>
#include <hip/hip_bf16.h>
#include <math.h>

constexpr int Lc = 256;
constexpr int Hc = 16;
constexpr int Dc = 2048;
constexpr int DHc = 128;
constexpr int LD = Lc * Dc;           // 524288
constexpr int OUT_LAST = 2 * LD - 1;
constexpr int NKT2 = 32;              // K-tiles per z-split (2 x 1024)

typedef __attribute__((ext_vector_type(8))) short short8;
typedef __attribute__((ext_vector_type(4))) float f32x4;
typedef __attribute__((ext_vector_type(4))) unsigned short ushort4v;

__device__ inline short f2bf(float f) {
  __hip_bfloat16 h = __float2bfloat16(f);
  return *reinterpret_cast<short*>(&h);
}
__device__ inline float bf2f(unsigned short s) {
  unsigned int u = ((unsigned int)s) << 16;
  return *reinterpret_cast<float*>(&u);
}

#define MFMA16(a, b, c) __builtin_amdgcn_mfma_f32_16x16x32_bf16(a, b, c, 0, 0, 0)

// ---------------------------------------------------------------------------
// Stage 1 (K-split 2, BM=64/BN=32, 4 waves, LDS dbuf depth-2):
// v_partial = x @ Wv (bf16 partials, no bias).
// grid (Dc/32=64, Lc/64=4, 2), 256 threads.
// ---------------------------------------------------------------------------
__global__ void gemm_v_split(const float* __restrict__ x,
                             const float* __restrict__ Wr,
                             const float* __restrict__ Wi,
                             __hip_bfloat16* __restrict__ vR0_,
                             __hip_bfloat16* __restrict__ vI0_,
                             __hip_bfloat16* __restrict__ vR1_,
                             __hip_bfloat16* __restrict__ vI1_) {
  __shared__ short As[2][64][36];                  // pad 36: stride 18 words
  __shared__ short BsR[2][32][36], BsI[2][32][36];
  const int tid = threadIdx.x;
  const int lane = tid & 63, wv = tid >> 6;        // 4 waves
  const int m0 = blockIdx.y * 64, n0 = blockIdx.x * 32;
  const int kbase = blockIdx.z * (NKT2 * 32);
  const int frow = lane & 15;
  const int koff = (lane >> 4) * 8;

  __hip_bfloat16* vR = blockIdx.z ? vR1_ : vR0_;
  __hip_bfloat16* vI = blockIdx.z ? vI1_ : vI0_;

  // staging: A slot (row, k-octet); B slot (col, k-octet, plane)
  const int arow = tid >> 2, akb = tid & 3;
  const int bcol = tid & 31, bkh = (tid >> 5) & 3, bplane = tid >> 7;

  const float* xb = x + (m0 + arow) * Dc + kbase + akb * 8;
  const float* wsrc = (bplane ? Wi : Wr) + (kbase + bkh * 8) * Dc + n0 + bcol;
  short (*Bdst)[32][36] = bplane ? BsI : BsR;

  f32x4 accR[2] = {}, accI[2] = {};

  f32x4 xa0, xc0, xa1, xc1;
  float bw0[8], bw1[8];

  auto LOAD0 = [&](int kt) {
    xa0 = *reinterpret_cast<const f32x4*>(xb + kt * 32);
    xc0 = *reinterpret_cast<const f32x4*>(xb + kt * 32 + 4);
#pragma unroll
    for (int j = 0; j < 8; ++j) bw0[j] = wsrc[(kt * 32 + j) * Dc];
  };
  auto LOAD1 = [&](int kt) {
    xa1 = *reinterpret_cast<const f32x4*>(xb + kt * 32);
    xc1 = *reinterpret_cast<const f32x4*>(xb + kt * 32 + 4);
#pragma unroll
    for (int j = 0; j < 8; ++j) bw1[j] = wsrc[(kt * 32 + j) * Dc];
  };
  auto STORE0 = [&](int buf) {
    short8 a;
    a[0]=f2bf(xa0[0]); a[1]=f2bf(xa0[1]); a[2]=f2bf(xa0[2]); a[3]=f2bf(xa0[3]);
    a[4]=f2bf(xc0[0]); a[5]=f2bf(xc0[1]); a[6]=f2bf(xc0[2]); a[7]=f2bf(xc0[3]);
    *reinterpret_cast<short8*>(&As[buf][arow][akb * 8]) = a;
    short8 w;
#pragma unroll
    for (int j = 0; j < 8; ++j) w[j] = f2bf(bw0[j]);
    *reinterpret_cast<short8*>(&Bdst[buf][bcol][bkh * 8]) = w;
  };
  auto STORE1 = [&](int buf) {
    short8 a;
    a[0]=f2bf(xa1[0]); a[1]=f2bf(xa1[1]); a[2]=f2bf(xa1[2]); a[3]=f2bf(xa1[3]);
    a[4]=f2bf(xc1[0]); a[5]=f2bf(xc1[1]); a[6]=f2bf(xc1[2]); a[7]=f2bf(xc1[3]);
    *reinterpret_cast<short8*>(&As[buf][arow][akb * 8]) = a;
    short8 w;
#pragma unroll
    for (int j = 0; j < 8; ++j) w[j] = f2bf(bw1[j]);
    *reinterpret_cast<short8*>(&Bdst[buf][bcol][bkh * 8]) = w;
  };
  auto COMPUTE = [&](int buf) {
    short8 a = *reinterpret_cast<short8*>(&As[buf][wv * 16 + frow][koff]);
#pragma unroll
    for (int ct = 0; ct < 2; ++ct) {
      short8 bR = *reinterpret_cast<short8*>(&BsR[buf][ct * 16 + frow][koff]);
      short8 bI = *reinterpret_cast<short8*>(&BsI[buf][ct * 16 + frow][koff]);
      accR[ct] = MFMA16(a, bR, accR[ct]);
      accI[ct] = MFMA16(a, bI, accI[ct]);
    }
  };

  LOAD0(0);
  LOAD1(1);
  STORE0(0);
  __syncthreads();

  for (int kt = 0; kt < NKT2; kt += 2) {
    if (kt + 2 < NKT2) LOAD0(kt + 2);
    STORE1(1);
    COMPUTE(0);
    __syncthreads();
    if (kt + 3 < NKT2) LOAD1(kt + 3);
    if (kt + 2 < NKT2) STORE0(0);
    COMPUTE(1);
    __syncthreads();
  }

#pragma unroll
  for (int ct = 0; ct < 2; ++ct)
#pragma unroll
    for (int r = 0; r < 4; ++r) {
      int row = m0 + wv * 16 + (lane >> 4) * 4 + r;
      int col = n0 + ct * 16 + frow;
      vR[row * Dc + col] = __float2bfloat16(accR[ct][r]);
      vI[row * Dc + col] = __float2bfloat16(accI[ct][r]);
    }
}

// ---------------------------------------------------------------------------
// Stage 2: o[s,n] = sum_m J[(m+s)%L, n/128] * (v0+v1+bv)[m,n]
// ---------------------------------------------------------------------------
__global__ void corr_v4(const __hip_bfloat16* __restrict__ vR0,
                        const __hip_bfloat16* __restrict__ vI0,
                        const __hip_bfloat16* __restrict__ vR1,
                        const __hip_bfloat16* __restrict__ vI1,
                        const float* __restrict__ bvR,
                        const float* __restrict__ bvI,
                        const float* __restrict__ JR,
                        const float* __restrict__ JI,
                        __hip_bfloat16* __restrict__ oR,
                        __hip_bfloat16* __restrict__ oI) {
  const int s = blockIdx.y;
  const int n0 = blockIdx.x * 256;
  const int tid = threadIdx.x;          // 0..63
  const int n = n0 + tid * 4;
  const int hl = (tid * 4) >> 7;
  __shared__ float jr[2][Lc], ji[2][Lc];
  const int h0 = n0 / DHc;
  for (int i = tid; i < 512; i += 64) {
    int hh = i >> 8, l = i & 255;
    jr[hh][l] = JR[l * Hc + h0 + hh];
    ji[hh][l] = JI[l * Hc + h0 + hh];
  }
  __syncthreads();

  f32x4 bvr4 = *reinterpret_cast<const f32x4*>(bvR + n);
  f32x4 bvi4 = *reinterpret_cast<const f32x4*>(bvI + n);

  float ar[4] = {0.f, 0.f, 0.f, 0.f}, ai[4] = {0.f, 0.f, 0.f, 0.f};
  const unsigned short* pR0 = reinterpret_cast<const unsigned short*>(vR0) + n;
  const unsigned short* pI0 = reinterpret_cast<const unsigned short*>(vI0) + n;
  const unsigned short* pR1 = reinterpret_cast<const unsigned short*>(vR1) + n;
  const unsigned short* pI1 = reinterpret_cast<const unsigned short*>(vI1) + n;
#pragma unroll 4
  for (int m = 0; m < Lc; ++m) {
    int l = (m + s) & (Lc - 1);
    float jjr = jr[hl][l], jji = ji[hl][l];
    ushort4v r40 = *reinterpret_cast<const ushort4v*>(pR0 + m * Dc);
    ushort4v i40 = *reinterpret_cast<const ushort4v*>(pI0 + m * Dc);
    ushort4v r41 = *reinterpret_cast<const ushort4v*>(pR1 + m * Dc);
    ushort4v i41 = *reinterpret_cast<const ushort4v*>(pI1 + m * Dc);
#pragma unroll
    for (int j = 0; j < 4; ++j) {
      float vr = bf2f(r40[j]) + bf2f(r41[j]) + bvr4[j];
      float vi = bf2f(i40[j]) + bf2f(i41[j]) + bvi4[j];
      ar[j] = fmaf(jjr, vr, ar[j]);
      ar[j] = fmaf(-jji, vi, ar[j]);
      ai[j] = fmaf(jjr, vi, ai[j]);
      ai[j] = fmaf(jji, vr, ai[j]);
    }
  }
  short oRp[4], oIp[4];
#pragma unroll
  for (int j = 0; j < 4; ++j) { oRp[j] = f2bf(ar[j]); oIp[j] = f2bf(ai[j]); }
  *reinterpret_cast<ushort4v*>(reinterpret_cast<unsigned short*>(oR) + s * Dc + n) =
      *reinterpret_cast<ushort4v*>(oRp);
  *reinterpret_cast<ushort4v*>(reinterpret_cast<unsigned short*>(oI) + s * Dc + n) =
      *reinterpret_cast<ushort4v*>(oIp);
}

// ---------------------------------------------------------------------------
// Stage 3 (K-split 2, BM=64/BN=32, 4 waves, LDS dbuf): y_partial = o @ W0.
// ---------------------------------------------------------------------------
__global__ void gemm_y_split(const __hip_bfloat16* __restrict__ oR,
                             const __hip_bfloat16* __restrict__ oI,
                             const float* __restrict__ Wr,
                             const float* __restrict__ Wi,
                             __hip_bfloat16* __restrict__ pR0_,
                             __hip_bfloat16* __restrict__ pI0_,
                             __hip_bfloat16* __restrict__ pR1_,
                             __hip_bfloat16* __restrict__ pI1_) {
  __shared__ short AsR[2][64][36], AsI[2][64][36];
  __shared__ short BsR[2][32][36], BsI[2][32][36];
  const int tid = threadIdx.x;
  const int lane = tid & 63, wv = tid >> 6;
  const int m0 = blockIdx.y * 64, n0 = blockIdx.x * 32;
  const int kbase = blockIdx.z * (NKT2 * 32);
  const int frow = lane & 15;
  const int koff = (lane >> 4) * 8;

  __hip_bfloat16* pR = blockIdx.z ? pR1_ : pR0_;
  __hip_bfloat16* pI = blockIdx.z ? pI1_ : pI0_;

  const int arow = tid >> 2, akb = tid & 3;
  const int bcol = tid & 31, bkh = (tid >> 5) & 3, bplane = tid >> 7;

  const short* aRb = reinterpret_cast<const short*>(oR) + (m0 + arow) * Dc + kbase + akb * 8;
  const short* aIb = reinterpret_cast<const short*>(oI) + (m0 + arow) * Dc + kbase + akb * 8;
  const float* wsrc = (bplane ? Wi : Wr) + (kbase + bkh * 8) * Dc + n0 + bcol;
  short (*Bdst)[32][36] = bplane ? BsI : BsR;

  f32x4 accR[2] = {}, accI[2] = {};

  short8 aR0, aI0, aR1, aI1;
  float bw0[8], bw1[8];

  auto LOAD0 = [&](int kt) {
    aR0 = *reinterpret_cast<const short8*>(aRb + kt * 32);
    aI0 = *reinterpret_cast<const short8*>(aIb + kt * 32);
#pragma unroll
    for (int j = 0; j < 8; ++j) bw0[j] = wsrc[(kt * 32 + j) * Dc];
  };
  auto LOAD1 = [&](int kt) {
    aR1 = *reinterpret_cast<const short8*>(aRb + kt * 32);
    aI1 = *reinterpret_cast<const short8*>(aIb + kt * 32);
#pragma unroll
    for (int j = 0; j < 8; ++j) bw1[j] = wsrc[(kt * 32 + j) * Dc];
  };
  auto STORE0 = [&](int buf) {
    *reinterpret_cast<short8*>(&AsR[buf][arow][akb * 8]) = aR0;
    *reinterpret_cast<short8*>(&AsI[buf][arow][akb * 8]) = aI0;
    short8 w;
#pragma unroll
    for (int j = 0; j < 8; ++j) w[j] = f2bf(bw0[j]);
    *reinterpret_cast<short8*>(&Bdst[buf][bcol][bkh * 8]) = w;
  };
  auto STORE1 = [&](int buf) {
    *reinterpret_cast<short8*>(&AsR[buf][arow][akb * 8]) = aR1;
    *reinterpret_cast<short8*>(&AsI[buf][arow][akb * 8]) = aI1;
    short8 w;
#pragma unroll
    for (int j = 0; j < 8; ++j) w[j] = f2bf(bw1[j]);
    *reinterpret_cast<short8*>(&Bdst[buf][bcol][bkh * 8]) = w;
  };
  auto COMPUTE = [&](int buf) {
    short8 aR = *reinterpret_cast<short8*>(&AsR[buf][wv * 16 + frow][koff]);
    short8 aI = *reinterpret_cast<short8*>(&AsI[buf][wv * 16 + frow][koff]);
    short8 aIn;
#pragma unroll
    for (int j = 0; j < 8; ++j) aIn[j] = aI[j] ^ (short)0x8000;
#pragma unroll
    for (int ct = 0; ct < 2; ++ct) {
      short8 bR = *reinterpret_cast<short8*>(&BsR[buf][ct * 16 + frow][koff]);
      short8 bI = *reinterpret_cast<short8*>(&BsI[buf][ct * 16 + frow][koff]);
      accR[ct] = MFMA16(aR, bR, accR[ct]);
      accR[ct] = MFMA16(aIn, bI, accR[ct]);
      accI[ct] = MFMA16(aR, bI, accI[ct]);
      accI[ct] = MFMA16(aI, bR, accI[ct]);
    }
  };

  LOAD0(0);
  LOAD1(1);
  STORE0(0);
  __syncthreads();

  for (int kt = 0; kt < NKT2; kt += 2) {
    if (kt + 2 < NKT2) LOAD0(kt + 2);
    STORE1(1);
    COMPUTE(0);
    __syncthreads();
    if (kt + 3 < NKT2) LOAD1(kt + 3);
    if (kt + 2 < NKT2) STORE0(0);
    COMPUTE(1);
    __syncthreads();
  }

#pragma unroll
  for (int ct = 0; ct < 2; ++ct)
#pragma unroll
    for (int r = 0; r < 4; ++r) {
      int row = m0 + wv * 16 + (lane >> 4) * 4 + r;
      int col = n0 + ct * 16 + frow;
      pR[row * Dc + col] = __float2bfloat16(accR[ct][r]);
      pI[row * Dc + col] = __float2bfloat16(accI[ct][r]);
    }
}

// ---------------------------------------------------------------------------
// Epilogue: y = p0 + p1 + b0; out = log_cosh(y); +1-shifted store.
// ---------------------------------------------------------------------------
__global__ void epilogue_y(const __hip_bfloat16* __restrict__ pR0b,
                           const __hip_bfloat16* __restrict__ pI0b,
                           const __hip_bfloat16* __restrict__ pR1b,
                           const __hip_bfloat16* __restrict__ pI1b,
                           const float* __restrict__ br,
                           const float* __restrict__ bi,
                           __hip_bfloat16* __restrict__ out) {
  const int idx0 = (blockIdx.x * 256 + threadIdx.x) * 4;
  const int col0 = idx0 & (Dc - 1);
  ushort4v r0 = *reinterpret_cast<const ushort4v*>(
      reinterpret_cast<const unsigned short*>(pR0b) + idx0);
  ushort4v i0 = *reinterpret_cast<const ushort4v*>(
      reinterpret_cast<const unsigned short*>(pI0b) + idx0);
  ushort4v r1 = *reinterpret_cast<const ushort4v*>(
      reinterpret_cast<const unsigned short*>(pR1b) + idx0);
  ushort4v i1 = *reinterpret_cast<const ushort4v*>(
      reinterpret_cast<const unsigned short*>(pI1b) + idx0);
  f32x4 br4 = *reinterpret_cast<const f32x4*>(br + col0);
  f32x4 bi4 = *reinterpret_cast<const f32x4*>(bi + col0);

  constexpr float LN2 = 0.69314718055994530942f;
#pragma unroll
  for (int j = 0; j < 4; ++j) {
    int idx = idx0 + j;
    float yr = bf2f(r0[j]) + bf2f(r1[j]) + br4[j];
    float yi = bf2f(i0[j]) + bf2f(i1[j]) + bi4[j];
    float sgn = (yr < 0.f) ? -1.f : 1.f;
    float zr = yr * sgn, zi = yi * sgn;
    float e = expf(-2.f * zr);
    float c = cosf(2.f * zi), s2 = sinf(2.f * zi);
    float pwr = e * c, pwi = -e * s2;
    float lr = 0.5f * log1pf(2.f * pwr + pwr * pwr + pwi * pwi);
    float li = atan2f(pwi, 1.f + pwr);
    float rr = zr + lr - LN2;
    float ri = zi + li;
    int f = idx * 2;
    out[f + 1] = __float2bfloat16(rr);        // validated[f]   = my[f+1]
    if (f + 2 <= OUT_LAST)
      out[f + 2] = __float2bfloat16(ri);      // validated[f+1] = my[f+2]
  }
}

extern "C" void kernel_launch(void* const* d_in, const int* in_sizes, int n_in,
                              void* d_out, int out_size, void* d_ws, size_t ws_size,
                              hipStream_t stream) {
  const float* x   = (const float*)d_in[0];
  const float* WvR = (const float*)d_in[1];
  const float* bvR = (const float*)d_in[2];
  const float* WvI = (const float*)d_in[3];
  const float* bvI = (const float*)d_in[4];
  const float* JR  = (const float*)d_in[5];
  const float* JI  = (const float*)d_in[6];
  const float* W0R = (const float*)d_in[7];
  const float* b0R = (const float*)d_in[8];
  const float* W0I = (const float*)d_in[9];
  const float* b0I = (const float*)d_in[10];

  // ws 4MB: quarters Q0..Q3 (LD bf16 elems each)
  __hip_bfloat16* Q0 = (__hip_bfloat16*)d_ws;
  __hip_bfloat16* Q1 = Q0 + LD;
  __hip_bfloat16* Q2 = Q1 + LD;
  __hip_bfloat16* Q3 = Q2 + LD;
  __hip_bfloat16* oR = (__hip_bfloat16*)d_out;
  __hip_bfloat16* oI = oR + LD;
  __hip_bfloat16* out = (__hip_bfloat16*)d_out;

  gemm_v_split<<<dim3(Dc / 32, Lc / 64, 2), 256, 0, stream>>>(
      x, WvR, WvI, Q0, Q1, Q2, Q3);
  corr_v4<<<dim3(Dc / 256, Lc), 64, 0, stream>>>(
      Q0, Q1, Q2, Q3, bvR, bvI, JR, JI, oR, oI);
  gemm_y_split<<<dim3(Dc / 32, Lc / 64, 2), 256, 0, stream>>>(
      oR, oI, W0R, W0I, Q0, Q1, Q2, Q3);
  epilogue_y<<<LD / 1024, 256, 0, stream>>>(
      Q0, Q1, Q2, Q3, b0R, b0I, out);
}